// Round 6
// baseline (10982.981 us; speedup 1.0000x reference)
//
#include <hip/hip_runtime.h>

typedef __attribute__((ext_vector_type(8))) short short8;
typedef __attribute__((ext_vector_type(4))) float f32x4;
typedef __attribute__((ext_vector_type(2))) unsigned long long u64x2;

constexpr int Bsz = 128;   // batch
constexpr int Tlen = 512;  // seq len
constexpr int Hd = 1024;   // hidden
constexpr int RS = 128 * 1024;  // ring slot elems ([128 rows][1024])
constexpr int NS = 8;           // ring depth

__device__ __forceinline__ unsigned short f2b(float f) {
  unsigned int u = __float_as_uint(f);
  u = (u + 0x7FFFu + ((u >> 16) & 1u)) >> 16;
  return (unsigned short)u;
}
__device__ __forceinline__ unsigned long long aload64(const unsigned long long* p) {
  return __hip_atomic_load(p, __ATOMIC_RELAXED, __HIP_MEMORY_SCOPE_AGENT);
}
__device__ __forceinline__ unsigned int aload32(const unsigned int* p) {
  return __hip_atomic_load(p, __ATOMIC_RELAXED, __HIP_MEMORY_SCOPE_AGENT);
}
__device__ __forceinline__ void astore32(unsigned int* p, unsigned int v) {
  __hip_atomic_store(p, v, __ATOMIC_RELAXED, __HIP_MEMORY_SCOPE_AGENT);
}

// Decoupled dataflow GRU. Four flag domains (layer x mh); 256 packed per-wave
// flags (flags[dom*256 + c*4 + w]). A block's phase waits only on the domain
// it reads: L0 waits {L0,mh}; L1's x-phase waits {L0,mh} (pre-satisfied: L0
// runs ahead), h-phase waits {L1,mh}. L1's x-phase GEMM executes INSIDE the
// h-rendezvous window. Rings depth-8; WAR enforced by an amortized
// every-4-rounds reader-domain check (flags >= r-3), polled in the reduce gap.
template <int LAYER>
__device__ __forceinline__ void run_layer(
    const int* __restrict__ src, const float* __restrict__ P,
    const unsigned short* __restrict__ Wh, const unsigned short* __restrict__ Wx,
    const float* __restrict__ bhh, const float* __restrict__ bih,
    float* __restrict__ dout,
    unsigned short* __restrict__ A0,    // [8][128][1024] h0 ring
    unsigned short* __restrict__ A1h,   // [8][128][1024] h1 ring
    unsigned short* __restrict__ A1x,   // [8][128][1024] y0 ring
    unsigned short* __restrict__ stg0,  // [2][64][1024] staging (L0 h / L1 x)
    unsigned short* __restrict__ stgH,  // [2][64][1024] staging (L1 h)
    unsigned int* __restrict__ flags,   // 4 doms x 256 packed per-wave flags
    unsigned int* __restrict__ lline,   // this group's 8 local flags (LLC)
    f32x4 (*__restrict__ red)[4][3][64],
    const int R0, const int J0, const int w, const int lane,
    const int m, const int tid)
{
  constexpr int PD = 3;
  constexpr int NQ = LAYER ? 4 : 3;
  const int lrow = lane >> 4;
  const int lcol = lane & 15;
  const int col = J0 + lcol;
  const int mh = R0 >> 6;
  const int domL0 = mh;
  const int domSelf = LAYER * 2 + mh;
  const int c = J0 >> 4;

  const float bhr = bhh[col], bhz = bhh[1024 + col], bhn = bhh[2048 + col];
  float gbr = 0.f, gbz = 0.f, gbn = 0.f;
  if (LAYER) { gbr = bih[col]; gbz = bih[1024 + col]; gbn = bih[2048 + col]; }

  // ---- resident h-part weights: 24 x short8 = 96 VGPR
  short8 wBh[3][8];
#pragma unroll
  for (int g = 0; g < 3; ++g) {
    const unsigned short* wp = Wh + (g * 1024 + col) * 1024 + w * 256 + lrow * 8;
#pragma unroll
    for (int ks = 0; ks < 8; ++ks)
      wBh[g][ks] = *(const short8*)(wp + ks * 32);
  }
  const unsigned short* wxp[3];
  if (LAYER) {
#pragma unroll
    for (int g = 0; g < 3; ++g)
      wxp[g] = Wx + (g * 1024 + col) * 1024 + w * 256 + lrow * 8;
  }

  const int myrow0 = R0 + w * 16 + lrow * 4;
  float hold[4] = {0.f, 0.f, 0.f, 0.f};

  for (int r = 0; r <= 512; ++r) {
    if (LAYER == 0 && r == 512) break;
    const bool active = LAYER ? (r >= 1) : true;
    const int scur = r & 7, snext = (r + 1) & 7;

    if (active) {
      f32x4 ar[4], az[4], anh[4], anx[4];
#pragma unroll
      for (int f = 0; f < 4; ++f) {
        ar[f]  = (f32x4){0.f, 0.f, 0.f, 0.f};
        az[f]  = (f32x4){0.f, 0.f, 0.f, 0.f};
        anh[f] = (f32x4){0.f, 0.f, 0.f, 0.f};
        anx[f] = (f32x4){0.f, 0.f, 0.f, 0.f};
      }
      float gpr[4], gpz[4], gpn[4];
      if (LAYER == 0) {
        int sv[4];
#pragma unroll
        for (int i = 0; i < 4; ++i) sv[i] = src[(myrow0 + i) * Tlen + r];
#pragma unroll
        for (int i = 0; i < 4; ++i) {
          const float* pr = P + sv[i] * 3072 + col;
          gpr[i] = pr[0]; gpz[i] = pr[1024]; gpn[i] = pr[2048];
        }
      } else {
#pragma unroll
        for (int i = 0; i < 4; ++i) { gpr[i] = gbr; gpz[i] = gbz; gpn[i] = gbn; }
      }

      unsigned short* s0 = stg0 + (r & 1) * 65536;
      unsigned short* sH = stgH + (r & 1) * 65536;

      auto detect = [&](int dom, unsigned tgt) {
        if (w == 0) {
          const unsigned int* fb = flags + dom * 256 + lane;
          for (;;) {
            const unsigned a = aload32(fb),        b = aload32(fb + 64),
                           c2 = aload32(fb + 128), d = aload32(fb + 192);
            if (__all(a >= tgt && b >= tgt && c2 >= tgt && d >= tgt)) break;
            __builtin_amdgcn_s_sleep(1);
          }
        }
        __syncthreads();
      };
      auto pullT = [&](const unsigned short* ring, unsigned short* stg) {
#pragma unroll
        for (int s = 0; s < 4; ++s) {
          const int cid = tid + s * 256;
          const int row = cid >> 4;
          const int kk = m * 128 + (cid & 15) * 8;
          const unsigned long long* ap = (const unsigned long long*)(
              ring + (R0 + row) * 1024 + kk);
          u64x2 v;
          v[0] = aload64(ap);
          v[1] = aload64(ap + 1);
          *(u64x2*)(stg + row * 1024 + kk) = v;
        }
      };
      auto localbar = [&](unsigned tgt) {
        __syncthreads();   // drains all waves' staging stores (vmcnt0)
        if (tid == 0) astore32(&lline[m], tgt);
        if (w == 0) {
          for (;;) {
            const unsigned v = (lane < 8) ? aload32(&lline[lane]) : tgt;
            if (__all(v >= tgt)) break;
          }
        }
        __syncthreads();
        asm volatile("buffer_inv sc0" ::: "memory");  // L1-only invalidate
      };
      auto gemm8 = [&](const unsigned short* stg, const short8 (&wB)[3][8],
                       f32x4 (&a0)[4], f32x4 (&a1)[4], f32x4 (&a2)[4]) {
        const unsigned short* rb[4];
#pragma unroll
        for (int f = 0; f < 4; ++f)
          rb[f] = stg + (f * 16 + lcol) * 1024 + w * 256 + lrow * 8;
        short8 abuf[PD][4];
#pragma unroll
        for (int s = 0; s < PD; ++s)
#pragma unroll
          for (int f = 0; f < 4; ++f)
            abuf[s][f] = *(const short8*)(rb[f] + s * 32);
#pragma unroll
        for (int ks = 0; ks < 8; ++ks) {
#pragma unroll
          for (int f = 0; f < 4; ++f) {
            const short8 a = abuf[ks % PD][f];
            a0[f] = __builtin_amdgcn_mfma_f32_16x16x32_bf16(a, wB[0][ks], a0[f], 0, 0, 0);
            a1[f] = __builtin_amdgcn_mfma_f32_16x16x32_bf16(a, wB[1][ks], a1[f], 0, 0, 0);
            a2[f] = __builtin_amdgcn_mfma_f32_16x16x32_bf16(a, wB[2][ks], a2[f], 0, 0, 0);
          }
          if (ks + PD < 8)
#pragma unroll
            for (int f = 0; f < 4; ++f)
              abuf[ks % PD][f] = *(const short8*)(rb[f] + (ks + PD) * 32);
        }
      };

      if (LAYER == 0) {
        if (r > 0) {
          detect(domL0, (unsigned)r);
          pullT(A0 + scur * RS, s0);
          localbar((unsigned)(r + 1));
          gemm8(s0, wBh, ar, az, anh);
        }
      } else {
        // ---- x phase: overlaps the h-rendezvous window (L0 runs ahead)
        detect(domL0, (unsigned)r);
        pullT(A1x + scur * RS, s0);
        localbar((unsigned)(2 * r));
        {
          const unsigned short* rb[4];
#pragma unroll
          for (int f = 0; f < 4; ++f)
            rb[f] = s0 + (f * 16 + lcol) * 1024 + w * 256 + lrow * 8;
          short8 abuf[PD][4];
#pragma unroll
          for (int s = 0; s < PD; ++s)
#pragma unroll
            for (int f = 0; f < 4; ++f)
              abuf[s][f] = *(const short8*)(rb[f] + s * 32);
          short8 wxb[4][3];
#pragma unroll
          for (int j = 0; j < 4; ++j)
#pragma unroll
            for (int g = 0; g < 3; ++g)
              wxb[j][g] = *(const short8*)(wxp[g] + j * 32);
#pragma unroll
          for (int ks = 0; ks < 8; ++ks) {
            const short8 br = wxb[ks % 4][0], bz = wxb[ks % 4][1], bn = wxb[ks % 4][2];
#pragma unroll
            for (int f = 0; f < 4; ++f) {
              const short8 a = abuf[ks % PD][f];
              ar[f]  = __builtin_amdgcn_mfma_f32_16x16x32_bf16(a, br, ar[f], 0, 0, 0);
              az[f]  = __builtin_amdgcn_mfma_f32_16x16x32_bf16(a, bz, az[f], 0, 0, 0);
              anx[f] = __builtin_amdgcn_mfma_f32_16x16x32_bf16(a, bn, anx[f], 0, 0, 0);
            }
            if (ks + PD < 8)
#pragma unroll
              for (int f = 0; f < 4; ++f)
                abuf[ks % PD][f] = *(const short8*)(rb[f] + (ks + PD) * 32);
            if (ks + 4 < 8)
#pragma unroll
              for (int g = 0; g < 3; ++g)
                wxb[ks % 4][g] = *(const short8*)(wxp[g] + (ks + 4) * 32);
          }
        }
        // ---- h phase: the true critical chain
        if (r > 1) {
          detect(domSelf, (unsigned)r);
          pullT(A1h + scur * RS, sH);
          localbar((unsigned)(2 * r + 1));
          gemm8(sH, wBh, ar, az, anh);
        }
      }

      // ---- cross-wave reduction
#pragma unroll
      for (int f = 0; f < 4; ++f) {
        if (f != w) {
          const int sl = (f < w) ? f : f - 1;
          red[w][0][sl][lane] = ar[f];
          red[w][1][sl][lane] = az[f];
          red[w][2][sl][lane] = anh[f];
          if (NQ == 4) red[w][3][sl][lane] = anx[f];
        }
      }
      // ---- amortized WAR check (depth-8 rings): readers >= r-3, every 4 rounds
      if (w == 0 && (r & 3) == 0 && r >= 8) {
        const unsigned tgt = (unsigned)(r - 3);
        const unsigned int* f1 = flags + (2 + mh) * 256 + lane;  // L1-mh readers
        const unsigned int* f0 = flags + mh * 256 + lane;        // L0-mh readers
        for (;;) {
          unsigned a = aload32(f1), b = aload32(f1 + 64),
                   c2 = aload32(f1 + 128), d = aload32(f1 + 192);
          bool ok = a >= tgt && b >= tgt && c2 >= tgt && d >= tgt;
          if (LAYER == 0) {
            unsigned e = aload32(f0), f = aload32(f0 + 64),
                     g = aload32(f0 + 128), h = aload32(f0 + 192);
            ok = ok && e >= tgt && f >= tgt && g >= tgt && h >= tgt;
          }
          if (__all(ok)) break;
          __builtin_amdgcn_s_sleep(1);
        }
      }
      __syncthreads();
      f32x4 sr  = (f32x4){0.f, 0.f, 0.f, 0.f};
      f32x4 sz_ = (f32x4){0.f, 0.f, 0.f, 0.f};
      f32x4 snh = (f32x4){0.f, 0.f, 0.f, 0.f};
      f32x4 snx = (f32x4){0.f, 0.f, 0.f, 0.f};
#pragma unroll
      for (int f = 0; f < 4; ++f)
        if (f == w) { sr = ar[f]; sz_ = az[f]; snh = anh[f]; if (NQ == 4) snx = anx[f]; }
#pragma unroll
      for (int ww = 0; ww < 4; ++ww) {
        if (ww != w) {
          const int sl = (w < ww) ? w : w - 1;
          sr  += red[ww][0][sl][lane];
          sz_ += red[ww][1][sl][lane];
          snh += red[ww][2][sl][lane];
          if (NQ == 4) snx += red[ww][3][sl][lane];
        }
      }

      // ---- 4-wave parallel epilogue
      const bool lastw = LAYER ? (r == 512) : (r == 511);
#pragma unroll
      for (int i = 0; i < 4; ++i) {
        const int row = myrow0 + i;
        float rg = sr[i] + gpr[i] + bhr;
        rg = 1.f / (1.f + __expf(-rg));
        float zg = sz_[i] + gpz[i] + bhz;
        zg = 1.f / (1.f + __expf(-zg));
        const float nx = (snx[i] + gpn[i]) + rg * (snh[i] + bhn);
        const float e2 = __expf(2.f * fabsf(nx));
        const float ng = copysignf(1.f - 2.f / (e2 + 1.f), nx);
        const float hnew = (1.f - zg) * ng + zg * hold[i];
        hold[i] = hnew;
        const unsigned int hb = (unsigned int)f2b(hnew);
        const unsigned int nb = (unsigned int)__shfl_down((int)hb, 1, 64);
        if ((lcol & 1) == 0) {
          const unsigned int pv = hb | (nb << 16);
          if (LAYER == 0) {
            astore32((unsigned int*)(A0 + snext * RS + row * 1024 + J0 + lcol), pv);
            astore32((unsigned int*)(A1x + snext * RS + row * 1024 + J0 + lcol), pv);
          } else {
            astore32((unsigned int*)(A1h + snext * RS + row * 1024 + J0 + lcol), pv);
          }
        }
        if (lastw) dout[LAYER * (Bsz * Hd) + row * Hd + col] = hnew;
      }
    }

    // ---- per-wave flag publish (own-wave drain only, no block barrier)
    asm volatile("s_waitcnt vmcnt(0)" ::: "memory");
    if (lane == 0)
      astore32(&flags[domSelf * 256 + c * 4 + w], (unsigned)(r + 1));
  }
}

__global__ void __launch_bounds__(256, 1) gru_persist(
    const int* __restrict__ src,
    const float* __restrict__ P,
    const unsigned short* __restrict__ Whh0b,
    const unsigned short* __restrict__ Whh1b,
    const unsigned short* __restrict__ Wih1b,
    const float* __restrict__ bhh0,
    const float* __restrict__ bih1,
    const float* __restrict__ bhh1,
    float* __restrict__ dout,
    unsigned short* __restrict__ A0,
    unsigned short* __restrict__ A1h,
    unsigned short* __restrict__ A1x,
    unsigned short* __restrict__ Stage,
    unsigned int* __restrict__ flags,
    unsigned int* __restrict__ lflags,
    int* __restrict__ taken)
{
  __shared__ f32x4 red[4][4][3][64];   // 48 KiB
  __shared__ int s_work;

  const int tid = threadIdx.x;

  if (tid == 0) {
    unsigned int xcc;
    asm volatile("s_getreg_b32 %0, hwreg(HW_REG_XCC_ID)" : "=s"(xcc));
    const int pref = ((int)(xcc & 7u)) * 32;
    int got = -1;
    for (int j = 0; j < 256; ++j) {
      const int idx = (pref + j) & 255;
      int expected = 0;
      if (__hip_atomic_compare_exchange_strong(&taken[idx], &expected, 1,
              __ATOMIC_RELAXED, __ATOMIC_RELAXED, __HIP_MEMORY_SCOPE_AGENT)) {
        got = idx; break;
      }
    }
    s_work = got;
  }
  __syncthreads();
  const int work = s_work;
  const int xcd_w = work >> 5;
  const int slot = work & 31;
  const int layer = (slot >> 4) & 1;
  const int m = (slot >> 1) & 7;
  const int c = xcd_w * 8 + m;
  const int mh = slot & 1;
  const int R0 = mh * 64;
  const int J0 = c * 16;

  const int w = tid >> 6;
  const int lane = tid & 63;

  // staging (per XCD, elems): L0 region [mh][2][65536] @0; L1 X @262144; L1 H @524288
  unsigned short* base = Stage + xcd_w * 786432;
  unsigned short* stg0 = base + (layer ? 262144 : 0) + mh * 131072;
  unsigned short* stgH = base + 524288 + mh * 131072;
  unsigned int* lline = lflags + (xcd_w * 4 + layer * 2 + mh) * 16;

  if (layer == 0)
    run_layer<0>(src, P, Whh0b, Wih1b, bhh0, bih1, dout, A0, A1h, A1x,
                 stg0, stgH, flags, lline, red, R0, J0, w, lane, m, tid);
  else
    run_layer<1>(src, P, Whh1b, Wih1b, bhh1, bih1, dout, A0, A1h, A1x,
                 stg0, stgH, flags, lline, red, R0, J0, w, lane, m, tid);
}

// ---------------- prep kernels ----------------
__global__ void __launch_bounds__(256) cvt_k(const float* __restrict__ s,
                                            unsigned short* __restrict__ d, int n) {
  const int i = (blockIdx.x * 256 + threadIdx.x) * 8;
  if (i >= n) return;
  const float4 a = *(const float4*)(s + i);
  const float4 b = *(const float4*)(s + i + 4);
  short8 o;
  o[0] = (short)f2b(a.x); o[1] = (short)f2b(a.y);
  o[2] = (short)f2b(a.z); o[3] = (short)f2b(a.w);
  o[4] = (short)f2b(b.x); o[5] = (short)f2b(b.y);
  o[6] = (short)f2b(b.z); o[7] = (short)f2b(b.w);
  *(short8*)(d + i) = o;
}

__global__ void __launch_bounds__(256) pemb_k(const float* __restrict__ emb,
                                             const float* __restrict__ wih0,
                                             const float* __restrict__ bih0,
                                             float* __restrict__ P) {
  __shared__ float se[64 * 64];
  const int g = blockIdx.x * 256 + threadIdx.x;
  const int v0 = blockIdx.y * 64;
  float acc[64];
#pragma unroll
  for (int i = 0; i < 64; ++i) acc[i] = 0.f;
  for (int kb = 0; kb < 8; ++kb) {
    __syncthreads();
#pragma unroll
    for (int s = 0; s < 4; ++s) {
      const int idx = threadIdx.x + s * 256;
      const int vv = idx >> 4, k4 = (idx & 15) * 4;
      *(float4*)(se + vv * 64 + k4) =
          *(const float4*)(emb + (v0 + vv) * 512 + kb * 64 + k4);
    }
    __syncthreads();
    float4 wv[16];
#pragma unroll
    for (int j = 0; j < 16; ++j)
      wv[j] = *(const float4*)(wih0 + g * 512 + kb * 64 + j * 4);
    for (int vv = 0; vv < 64; ++vv) {
      const float* er = se + vv * 64;
      float s0 = acc[vv];
#pragma unroll
      for (int j = 0; j < 16; ++j) {
        const float4 e = *(const float4*)(er + j * 4);
        s0 += wv[j].x * e.x + wv[j].y * e.y + wv[j].z * e.z + wv[j].w * e.w;
      }
      acc[vv] = s0;
    }
  }
  const float bb = bih0[g];
  for (int vv = 0; vv < 64; ++vv) P[(v0 + vv) * 3072 + g] = acc[vv] + bb;
}

__global__ void zero_k(unsigned int* flags, int* taken, unsigned int* lflags) {
  const int i = threadIdx.x;           // 0..255
  flags[i] = 0u; flags[i + 256] = 0u; flags[i + 512] = 0u; flags[i + 768] = 0u;
  taken[i] = 0;
  lflags[i] = 0u;
  lflags[i + 256] = 0u;
}

extern "C" void kernel_launch(void* const* d_in, const int* in_sizes, int n_in,
                              void* d_out, int out_size, void* d_ws, size_t ws_size,
                              hipStream_t stream) {
  const int* src = (const int*)d_in[0];
  const float* emb = (const float*)d_in[1];
  const float* wih0 = (const float*)d_in[2];
  const float* whh0 = (const float*)d_in[3];
  const float* bih0 = (const float*)d_in[4];
  const float* bhh0 = (const float*)d_in[5];
  const float* wih1 = (const float*)d_in[6];
  const float* whh1 = (const float*)d_in[7];
  const float* bih1 = (const float*)d_in[8];
  const float* bhh1 = (const float*)d_in[9];
  float* dout = (float*)d_out;

  char* p = (char*)d_ws;
  unsigned short* A0    = (unsigned short*)p;                    // 2097152 B
  unsigned short* A1h   = (unsigned short*)(p + 2097152);        // 2097152 B
  unsigned short* A1x   = (unsigned short*)(p + 4194304);        // 2097152 B
  unsigned short* Whh0b = (unsigned short*)(p + 6291456);        // 6291456 B
  unsigned short* Whh1b = (unsigned short*)(p + 12582912);       // 6291456 B
  unsigned short* Wih1b = (unsigned short*)(p + 18874368);       // 6291456 B
  float* P              = (float*)(p + 25165824);                // 6291456 B
  unsigned int* flags   = (unsigned int*)(p + 31457280);         // 4096 B
  unsigned int* lflags  = (unsigned int*)(p + 31461376);         // 2048 B
  int* taken            = (int*)(p + 31463424);                  // 1024 B
  unsigned short* Stage = (unsigned short*)(p + 31464448);       // 12582912 B
  // total ws use: ~42.0 MB

  constexpr int NW = 3072 * 1024;
  hipLaunchKernelGGL(cvt_k, dim3(NW / (256 * 8)), dim3(256), 0, stream, whh0, Whh0b, NW);
  hipLaunchKernelGGL(cvt_k, dim3(NW / (256 * 8)), dim3(256), 0, stream, whh1, Whh1b, NW);
  hipLaunchKernelGGL(cvt_k, dim3(NW / (256 * 8)), dim3(256), 0, stream, wih1, Wih1b, NW);
  hipLaunchKernelGGL(pemb_k, dim3(12, 8), dim3(256), 0, stream, emb, wih0, bih0, P);
  hipLaunchKernelGGL(zero_k, dim3(1), dim3(256), 0, stream, flags, taken, lflags);

  hipLaunchKernelGGL(gru_persist, dim3(256), dim3(256), 0, stream,
                     src, P, Whh0b, Whh1b, Wih1b, bhh0, bih1, bhh1,
                     dout, A0, A1h, A1x, Stage, flags, lflags, taken);
}

// Round 7
// 8716.183 us; speedup vs baseline: 1.2601x; 1.2601x over previous
//
#include <hip/hip_runtime.h>

typedef __attribute__((ext_vector_type(8))) short short8;
typedef __attribute__((ext_vector_type(4))) float f32x4;

constexpr int Bsz = 128;   // batch
constexpr int Tlen = 512;  // seq len
constexpr int Hd = 1024;   // hidden
constexpr int RS = 128 * 1024;  // ring slot elems ([128][1024] bf16)

__device__ __forceinline__ unsigned short f2b(float f) {
  unsigned int u = __float_as_uint(f);
  u = (u + 0x7FFFu + ((u >> 16) & 1u)) >> 16;
  return (unsigned short)u;
}
__device__ __forceinline__ unsigned int aload32(const unsigned int* p) {
  return __hip_atomic_load(p, __ATOMIC_RELAXED, __HIP_MEMORY_SCOPE_AGENT);
}
__device__ __forceinline__ void astore32(unsigned int* p, unsigned int v) {
  __hip_atomic_store(p, v, __ATOMIC_RELAXED, __HIP_MEMORY_SCOPE_AGENT);
}

// One-chain-per-round dataflow GRU.
// Rings (depth 4, LLC-resident, written with sc1 stores): A0 (h0), A1h (h1),
// A1x (y0). GEMM reads are PLAIN cacheable loads -> per-XCD L2 dedups the 8
// same-tile readers to one LLC fetch per line. Coherence: per-XCD invalidator
// (slot 0) does one fence(acquire,agent) per round after waiting all-domains
// >= r-2, publishes invflag=r+1; consumers require invflag >= r in their
// detect. Per-CU stale L1 handled by buffer_inv sc0 after detect.
template <int LAYER>
__device__ __forceinline__ void run_layer(
    const int* __restrict__ src, const float* __restrict__ P,
    const unsigned short* __restrict__ Wh, const unsigned short* __restrict__ Wx,
    const float* __restrict__ bhh, const float* __restrict__ bih,
    float* __restrict__ dout,
    unsigned short* __restrict__ A0r,
    unsigned short* __restrict__ A1hr,
    unsigned short* __restrict__ A1xr,
    unsigned int* __restrict__ flags,     // 4 doms x 64 packed flags
    unsigned int* __restrict__ invflags,  // 8 x 16-dword lines
    f32x4 (*__restrict__ red)[4][3][64],
    const int R0, const int J0, const int w, const int lane,
    const int tid, const int c, const int xcd, const bool isInv)
{
  constexpr int NQ = LAYER ? 4 : 3;
  const int lrow = lane >> 4;
  const int lcol = lane & 15;
  const int col = J0 + lcol;
  const int mh = R0 >> 6;
  const int dom = LAYER * 2 + mh;

  const float bhr = bhh[col], bhz = bhh[1024 + col], bhn = bhh[2048 + col];
  float gbr = 0.f, gbz = 0.f, gbn = 0.f;
  if (LAYER) { gbr = bih[col]; gbz = bih[1024 + col]; gbn = bih[2048 + col]; }

  // ---- register-resident weights (immune to per-round L2 invalidation)
  short8 wBh[3][8];
#pragma unroll
  for (int g = 0; g < 3; ++g) {
    const unsigned short* wp = Wh + (g * 1024 + col) * 1024 + w * 256 + lrow * 8;
#pragma unroll
    for (int ks = 0; ks < 8; ++ks) wBh[g][ks] = *(const short8*)(wp + ks * 32);
  }
  short8 wBx[3][8];
  if (LAYER) {
#pragma unroll
    for (int g = 0; g < 3; ++g) {
      const unsigned short* wp = Wx + (g * 1024 + col) * 1024 + w * 256 + lrow * 8;
#pragma unroll
      for (int ks = 0; ks < 8; ++ks) wBx[g][ks] = *(const short8*)(wp + ks * 32);
    }
  }

  const int myrow0 = R0 + w * 16 + lrow * 4;
  float hold[4] = {0.f, 0.f, 0.f, 0.f};

  for (int r = 0; r <= 512; ++r) {
    if (LAYER == 0 && r == 512) break;
    const bool active = LAYER ? (r >= 1) : true;

    if (active) {
      const int scur = r & 3, snext = (r + 1) & 3;

      // ---- constant-data gathers into registers (pre-detect; P/src immutable)
      float gpr[4], gpz[4], gpn[4];
      if (LAYER == 0) {
        int sv[4];
#pragma unroll
        for (int i = 0; i < 4; ++i) sv[i] = src[(myrow0 + i) * Tlen + r];
#pragma unroll
        for (int i = 0; i < 4; ++i) {
          const float* pr = P + sv[i] * 3072 + col;
          gpr[i] = pr[0]; gpz[i] = pr[1024]; gpn[i] = pr[2048];
        }
      } else {
#pragma unroll
        for (int i = 0; i < 4; ++i) { gpr[i] = gbr; gpz[i] = gbz; gpn[i] = gbn; }
      }

      // ---- detect: the single rendezvous chain of the round
      const bool doDetect = (LAYER == 1) || (r >= 1);
      if (doDetect) {
        if (w == 0) {
          const unsigned tgt = (unsigned)r;
          if (isInv) {
            // invalidator (L0,mh0,m0): own dep + all-domains >= r-2, then L2 inv
            const unsigned tA = (r >= 2) ? (unsigned)(r - 2) : 0u;
            const unsigned int* f0 = flags + 0 * 64 + lane;
            const unsigned int* f1 = flags + 1 * 64 + lane;
            const unsigned int* f2 = flags + 2 * 64 + lane;
            const unsigned int* f3 = flags + 3 * 64 + lane;
            for (;;) {
              const unsigned a = aload32(f0), b = aload32(f1),
                             d = aload32(f2), e = aload32(f3);
              if (__all(a >= tgt && b >= tA && d >= tA && e >= tA)) break;
              __builtin_amdgcn_s_sleep(1);
            }
            __builtin_amdgcn_fence(__ATOMIC_ACQUIRE, "agent");  // L2 invalidate
            if (lane == 0) astore32(&invflags[xcd * 16], (unsigned)(r + 1));
          } else {
            const unsigned int* fp = flags + mh * 64 + lane;        // L0-mh dom
            const unsigned int* fs = flags + (2 + mh) * 64 + lane;  // L1-mh dom
            const unsigned tgtS = LAYER ? tgt : ((r >= 2) ? (unsigned)(r - 2) : 0u);
            const unsigned int* iv = &invflags[xcd * 16];
            for (;;) {
              const unsigned a = aload32(fp), b = aload32(fs), k = aload32(iv);
              if (__all(a >= tgt && b >= tgtS && k >= tgt)) break;
              __builtin_amdgcn_s_sleep(1);
            }
          }
        }
        __syncthreads();
        asm volatile("buffer_inv sc0" ::: "memory");  // per-CU L1 invalidate
      } else if (isInv) {
        // L0 r==0: nothing to read anywhere; prime the invflag chain
        if (w == 0 && lane == 0) astore32(&invflags[xcd * 16], 1u);
      }

      f32x4 ar[4], az[4], anh[4], anx[4];
#pragma unroll
      for (int f = 0; f < 4; ++f) {
        ar[f]  = (f32x4){0.f, 0.f, 0.f, 0.f};
        az[f]  = (f32x4){0.f, 0.f, 0.f, 0.f};
        anh[f] = (f32x4){0.f, 0.f, 0.f, 0.f};
        anx[f] = (f32x4){0.f, 0.f, 0.f, 0.f};
      }

      // ---- GEMM: direct plain ring loads (L2-shared within XCD), PD=4
      if (LAYER == 0) {
        if (r >= 1) {
          const unsigned short* rb[4];
#pragma unroll
          for (int f = 0; f < 4; ++f)
            rb[f] = A0r + scur * RS + (R0 + f * 16 + lcol) * 1024 + w * 256 + lrow * 8;
          short8 ab[4][4];
#pragma unroll
          for (int s = 0; s < 4; ++s)
#pragma unroll
            for (int f = 0; f < 4; ++f) ab[s][f] = *(const short8*)(rb[f] + s * 32);
#pragma unroll
          for (int ks = 0; ks < 8; ++ks) {
#pragma unroll
            for (int f = 0; f < 4; ++f) {
              const short8 a = ab[ks & 3][f];
              ar[f]  = __builtin_amdgcn_mfma_f32_16x16x32_bf16(a, wBh[0][ks], ar[f], 0, 0, 0);
              az[f]  = __builtin_amdgcn_mfma_f32_16x16x32_bf16(a, wBh[1][ks], az[f], 0, 0, 0);
              anh[f] = __builtin_amdgcn_mfma_f32_16x16x32_bf16(a, wBh[2][ks], anh[f], 0, 0, 0);
            }
            if (ks + 4 < 8)
#pragma unroll
              for (int f = 0; f < 4; ++f)
                ab[ks & 3][f] = *(const short8*)(rb[f] + (ks + 4) * 32);
          }
        }
      } else {
        const unsigned short* rbx[4];
        const unsigned short* rbh[4];
#pragma unroll
        for (int f = 0; f < 4; ++f) {
          const int ro = (R0 + f * 16 + lcol) * 1024 + w * 256 + lrow * 8;
          rbx[f] = A1xr + scur * RS + ro;
          rbh[f] = A1hr + scur * RS + ro;
        }
        if (r >= 2) {
          // combined 16-step sequence: 0..7 = x (y0), 8..15 = h (h1)
          short8 ab[4][4];
#pragma unroll
          for (int s = 0; s < 4; ++s)
#pragma unroll
            for (int f = 0; f < 4; ++f) ab[s][f] = *(const short8*)(rbx[f] + s * 32);
#pragma unroll
          for (int ks = 0; ks < 16; ++ks) {
            const short8 br = (ks < 8) ? wBx[0][ks] : wBh[0][ks - 8];
            const short8 bz = (ks < 8) ? wBx[1][ks] : wBh[1][ks - 8];
            const short8 bn = (ks < 8) ? wBx[2][ks] : wBh[2][ks - 8];
#pragma unroll
            for (int f = 0; f < 4; ++f) {
              const short8 a = ab[ks & 3][f];
              ar[f] = __builtin_amdgcn_mfma_f32_16x16x32_bf16(a, br, ar[f], 0, 0, 0);
              az[f] = __builtin_amdgcn_mfma_f32_16x16x32_bf16(a, bz, az[f], 0, 0, 0);
              if (ks < 8)
                anx[f] = __builtin_amdgcn_mfma_f32_16x16x32_bf16(a, bn, anx[f], 0, 0, 0);
              else
                anh[f] = __builtin_amdgcn_mfma_f32_16x16x32_bf16(a, bn, anh[f], 0, 0, 0);
            }
            const int kn = ks + 4;
            if (kn < 16) {
#pragma unroll
              for (int f = 0; f < 4; ++f)
                ab[ks & 3][f] = *(const short8*)(
                    (kn < 8) ? (rbx[f] + kn * 32) : (rbh[f] + (kn - 8) * 32));
            }
          }
        } else {
          // r == 1: x-part only (h1[0] == 0)
          short8 ab[4][4];
#pragma unroll
          for (int s = 0; s < 4; ++s)
#pragma unroll
            for (int f = 0; f < 4; ++f) ab[s][f] = *(const short8*)(rbx[f] + s * 32);
#pragma unroll
          for (int ks = 0; ks < 8; ++ks) {
#pragma unroll
            for (int f = 0; f < 4; ++f) {
              const short8 a = ab[ks & 3][f];
              ar[f]  = __builtin_amdgcn_mfma_f32_16x16x32_bf16(a, wBx[0][ks], ar[f], 0, 0, 0);
              az[f]  = __builtin_amdgcn_mfma_f32_16x16x32_bf16(a, wBx[1][ks], az[f], 0, 0, 0);
              anx[f] = __builtin_amdgcn_mfma_f32_16x16x32_bf16(a, wBx[2][ks], anx[f], 0, 0, 0);
            }
            if (ks + 4 < 8)
#pragma unroll
              for (int f = 0; f < 4; ++f)
                ab[ks & 3][f] = *(const short8*)(rbx[f] + (ks + 4) * 32);
          }
        }
      }

      // ---- cross-wave reduction: wave w sends f != w, keeps f == w
#pragma unroll
      for (int f = 0; f < 4; ++f) {
        if (f != w) {
          const int sl = (f < w) ? f : f - 1;
          red[w][0][sl][lane] = ar[f];
          red[w][1][sl][lane] = az[f];
          red[w][2][sl][lane] = anh[f];
          if (NQ == 4) red[w][3][sl][lane] = anx[f];
        }
      }
      __syncthreads();
      f32x4 sr  = (f32x4){0.f, 0.f, 0.f, 0.f};
      f32x4 sz_ = (f32x4){0.f, 0.f, 0.f, 0.f};
      f32x4 snh = (f32x4){0.f, 0.f, 0.f, 0.f};
      f32x4 snx = (f32x4){0.f, 0.f, 0.f, 0.f};
#pragma unroll
      for (int f = 0; f < 4; ++f)
        if (f == w) { sr = ar[f]; sz_ = az[f]; snh = anh[f]; if (NQ == 4) snx = anx[f]; }
#pragma unroll
      for (int ww = 0; ww < 4; ++ww) {
        if (ww != w) {
          const int sl = (w < ww) ? w : w - 1;
          sr  += red[ww][0][sl][lane];
          sz_ += red[ww][1][sl][lane];
          snh += red[ww][2][sl][lane];
          if (NQ == 4) snx += red[ww][3][sl][lane];
        }
      }

      // ---- 4-wave parallel epilogue (ring stores are sc1 -> LLC)
      const bool lastw = LAYER ? (r == 512) : (r == 511);
#pragma unroll
      for (int i = 0; i < 4; ++i) {
        const int row = myrow0 + i;
        float rg = sr[i] + gpr[i] + bhr;
        rg = 1.f / (1.f + __expf(-rg));
        float zg = sz_[i] + gpz[i] + bhz;
        zg = 1.f / (1.f + __expf(-zg));
        const float nx = (snx[i] + gpn[i]) + rg * (snh[i] + bhn);
        const float e2 = __expf(2.f * fabsf(nx));
        const float ng = copysignf(1.f - 2.f / (e2 + 1.f), nx);
        const float hnew = (1.f - zg) * ng + zg * hold[i];
        hold[i] = hnew;
        const unsigned int hb = (unsigned int)f2b(hnew);
        const unsigned int nb = (unsigned int)__shfl_down((int)hb, 1, 64);
        if ((lcol & 1) == 0) {
          const unsigned int pv = hb | (nb << 16);
          if (LAYER == 0) {
            astore32((unsigned int*)(A0r + snext * RS + row * 1024 + J0 + lcol), pv);
            astore32((unsigned int*)(A1xr + snext * RS + row * 1024 + J0 + lcol), pv);
          } else {
            astore32((unsigned int*)(A1hr + snext * RS + row * 1024 + J0 + lcol), pv);
          }
        }
        if (lastw) dout[LAYER * (Bsz * Hd) + row * Hd + col] = hnew;
      }
    }

    // ---- publish my round flag (all waves' sc1 stores drained by barrier)
    __syncthreads();
    if (tid == 0) astore32(&flags[dom * 64 + c], (unsigned)(r + 1));
  }
}

__global__ void __launch_bounds__(256, 1) gru_persist(
    const int* __restrict__ src,
    const float* __restrict__ P,
    const unsigned short* __restrict__ Whh0b,
    const unsigned short* __restrict__ Whh1b,
    const unsigned short* __restrict__ Wih1b,
    const float* __restrict__ bhh0,
    const float* __restrict__ bih1,
    const float* __restrict__ bhh1,
    float* __restrict__ dout,
    unsigned short* __restrict__ A0,
    unsigned short* __restrict__ A1h,
    unsigned short* __restrict__ A1x,
    unsigned int* __restrict__ flags,
    unsigned int* __restrict__ invflags,
    int* __restrict__ taken)
{
  __shared__ f32x4 red[4][4][3][64];   // 48 KiB
  __shared__ int s_work;

  const int tid = threadIdx.x;

  // ---- XCD-affinity work claiming: the 8 c-blocks of a group share the
  // XCD's L2, which dedups their identical ring-tile reads.
  if (tid == 0) {
    unsigned int xcc;
    asm volatile("s_getreg_b32 %0, hwreg(HW_REG_XCC_ID)" : "=s"(xcc));
    const int pref = ((int)(xcc & 7u)) * 32;
    int got = -1;
    for (int j = 0; j < 256; ++j) {
      const int idx = (pref + j) & 255;
      int expected = 0;
      if (__hip_atomic_compare_exchange_strong(&taken[idx], &expected, 1,
              __ATOMIC_RELAXED, __ATOMIC_RELAXED, __HIP_MEMORY_SCOPE_AGENT)) {
        got = idx; break;
      }
    }
    s_work = got;
  }
  __syncthreads();
  const int work = s_work;
  const int xcd_w = work >> 5;
  const int slot = work & 31;
  const int layer = (slot >> 4) & 1;
  const int m = (slot >> 1) & 7;
  const int c = xcd_w * 8 + m;
  const int mh = slot & 1;
  const int R0 = mh * 64;
  const int J0 = c * 16;
  const bool isInv = (slot == 0);   // per-XCD invalidator (L0, mh0, m0)

  const int w = tid >> 6;
  const int lane = tid & 63;

  if (layer == 0)
    run_layer<0>(src, P, Whh0b, Wih1b, bhh0, bih1, dout, A0, A1h, A1x,
                 flags, invflags, red, R0, J0, w, lane, tid, c, xcd_w, isInv);
  else
    run_layer<1>(src, P, Whh1b, Wih1b, bhh1, bih1, dout, A0, A1h, A1x,
                 flags, invflags, red, R0, J0, w, lane, tid, c, xcd_w, false);
}

// ---------------- prep kernels ----------------
__global__ void __launch_bounds__(256) cvt_k(const float* __restrict__ s,
                                            unsigned short* __restrict__ d, int n) {
  const int i = (blockIdx.x * 256 + threadIdx.x) * 8;
  if (i >= n) return;
  const float4 a = *(const float4*)(s + i);
  const float4 b = *(const float4*)(s + i + 4);
  short8 o;
  o[0] = (short)f2b(a.x); o[1] = (short)f2b(a.y);
  o[2] = (short)f2b(a.z); o[3] = (short)f2b(a.w);
  o[4] = (short)f2b(b.x); o[5] = (short)f2b(b.y);
  o[6] = (short)f2b(b.z); o[7] = (short)f2b(b.w);
  *(short8*)(d + i) = o;
}

__global__ void __launch_bounds__(256) pemb_k(const float* __restrict__ emb,
                                             const float* __restrict__ wih0,
                                             const float* __restrict__ bih0,
                                             float* __restrict__ P) {
  __shared__ float se[64 * 64];
  const int g = blockIdx.x * 256 + threadIdx.x;
  const int v0 = blockIdx.y * 64;
  float acc[64];
#pragma unroll
  for (int i = 0; i < 64; ++i) acc[i] = 0.f;
  for (int kb = 0; kb < 8; ++kb) {
    __syncthreads();
#pragma unroll
    for (int s = 0; s < 4; ++s) {
      const int idx = threadIdx.x + s * 256;
      const int vv = idx >> 4, k4 = (idx & 15) * 4;
      *(float4*)(se + vv * 64 + k4) =
          *(const float4*)(emb + (v0 + vv) * 512 + kb * 64 + k4);
    }
    __syncthreads();
    float4 wv[16];
#pragma unroll
    for (int j = 0; j < 16; ++j)
      wv[j] = *(const float4*)(wih0 + g * 512 + kb * 64 + j * 4);
    for (int vv = 0; vv < 64; ++vv) {
      const float* er = se + vv * 64;
      float s0 = acc[vv];
#pragma unroll
      for (int j = 0; j < 16; ++j) {
        const float4 e = *(const float4*)(er + j * 4);
        s0 += wv[j].x * e.x + wv[j].y * e.y + wv[j].z * e.z + wv[j].w * e.w;
      }
      acc[vv] = s0;
    }
  }
  const float bb = bih0[g];
  for (int vv = 0; vv < 64; ++vv) P[(v0 + vv) * 3072 + g] = acc[vv] + bb;
}

__global__ void zero_k(unsigned int* flags, int* taken, unsigned int* invflags) {
  const int i = threadIdx.x;           // 0..255
  flags[i] = 0u;                       // 4 doms x 64
  taken[i] = 0;
  if (i < 128) invflags[i] = 0u;       // 8 x 16
}

extern "C" void kernel_launch(void* const* d_in, const int* in_sizes, int n_in,
                              void* d_out, int out_size, void* d_ws, size_t ws_size,
                              hipStream_t stream) {
  const int* src = (const int*)d_in[0];
  const float* emb = (const float*)d_in[1];
  const float* wih0 = (const float*)d_in[2];
  const float* whh0 = (const float*)d_in[3];
  const float* bih0 = (const float*)d_in[4];
  const float* bhh0 = (const float*)d_in[5];
  const float* wih1 = (const float*)d_in[6];
  const float* whh1 = (const float*)d_in[7];
  const float* bih1 = (const float*)d_in[8];
  const float* bhh1 = (const float*)d_in[9];
  float* dout = (float*)d_out;

  char* p = (char*)d_ws;
  unsigned short* A0    = (unsigned short*)p;                    // 4 x 256KB = 1 MB
  unsigned short* A1h   = (unsigned short*)(p + 1048576);        // 1 MB
  unsigned short* A1x   = (unsigned short*)(p + 2097152);        // 1 MB
  unsigned short* Whh0b = (unsigned short*)(p + 3145728);        // 6291456 B
  unsigned short* Whh1b = (unsigned short*)(p + 9437184);        // 6291456 B
  unsigned short* Wih1b = (unsigned short*)(p + 15728640);       // 6291456 B
  float* P              = (float*)(p + 22020096);                // 6291456 B
  unsigned int* flags   = (unsigned int*)(p + 28311552);         // 1024 B
  unsigned int* invflags= (unsigned int*)(p + 28312576);         // 512 B
  int* taken            = (int*)(p + 28313600);                  // 1024 B
  // total ws use: ~28.3 MB

  constexpr int NW = 3072 * 1024;
  hipLaunchKernelGGL(cvt_k, dim3(NW / (256 * 8)), dim3(256), 0, stream, whh0, Whh0b, NW);
  hipLaunchKernelGGL(cvt_k, dim3(NW / (256 * 8)), dim3(256), 0, stream, whh1, Whh1b, NW);
  hipLaunchKernelGGL(cvt_k, dim3(NW / (256 * 8)), dim3(256), 0, stream, wih1, Wih1b, NW);
  hipLaunchKernelGGL(pemb_k, dim3(12, 8), dim3(256), 0, stream, emb, wih0, bih0, P);
  hipLaunchKernelGGL(zero_k, dim3(1), dim3(256), 0, stream, flags, taken, invflags);

  hipLaunchKernelGGL(gru_persist, dim3(256), dim3(256), 0, stream,
                     src, P, Whh0b, Whh1b, Wih1b, bhh0, bih1, bhh1,
                     dout, A0, A1h, A1x, flags, invflags, taken);
}